// Round 9
// baseline (618.321 us; speedup 1.0000x reference)
//
#include <hip/hip_runtime.h>
#include <math.h>

#define NV 4096
#define NNL ((size_t)NV * NV)
#define BM 128
#define BK 32
#define NKT (NV / BK)

typedef __bf16 bf16_t;
typedef __bf16 bf16x4 __attribute__((ext_vector_type(4)));
typedef __bf16 bf16x8 __attribute__((ext_vector_type(8)));
typedef float f32x4 __attribute__((ext_vector_type(4)));

struct FC { float c[6][4]; };   // c[0] = 0.5*c~0, c[1..5] = c~1..c~5 (x 64)

// ---------------------------------------------------------------------------
// Init: T1 = L - I (bf16)
// ---------------------------------------------------------------------------
__global__ __launch_bounds__(256) void init_kernel(const float* __restrict__ L,
                                                   bf16_t* __restrict__ T1) {
  const size_t stride = (size_t)gridDim.x * blockDim.x;
  for (size_t q = (size_t)blockIdx.x * blockDim.x + threadIdx.x; q < NNL / 4; q += stride) {
    const size_t i0 = q * 4;
    const int row = (int)(i0 >> 12);
    const int col0 = (int)(i0 & 4095);
    float4 lv = ((const float4*)L)[q];
    float lvv[4] = {lv.x, lv.y, lv.z, lv.w};
    bf16x4 tb;
#pragma unroll
    for (int e = 0; e < 4; ++e)
      tb[e] = (bf16_t)(lvv[e] - ((col0 + e == row) ? 1.0f : 0.0f));
    *(bf16x4*)(T1 + i0) = tb;
  }
}

// ---------------------------------------------------------------------------
// Chebyshev GEMM on the LOWER-TRIANGULAR 128-block grid (528 tiles, bm>=bn),
// m97 K-loop + swapped-operand epilogue + fused LDS-transpose mirror.
//   MODE 0: T2 = 2*T1*T1 - I            (528 blocks)
//   MODE 1: wid<528:  T3 = 2*T1*T2 - T1 (1056 blocks, merged — both depend
//           wid>=528: T4 = 2*T2*T2 - I   only on T2, no mutual dependency)
//   MODE 2: T5 = 2*T1*T4 - T3, FUSED OUTPUT: writes the 4 f32 output planes
//           out_f = 0.5c0*I + sum_{k=1..5} c_k*T_k directly (no Tnew, no flush)
// ---------------------------------------------------------------------------
template <int MODE>
__global__ __launch_bounds__(256, 3) void cheb(
    const bf16_t* __restrict__ T1, const bf16_t* __restrict__ T2,
    const bf16_t* __restrict__ T3, const bf16_t* __restrict__ T4,
    bf16_t* __restrict__ O1, bf16_t* __restrict__ O2,
    float* __restrict__ out, FC fc) {
  __shared__ union {
    struct { bf16_t A[2][BM][BK]; bf16_t B[2][BM][BK]; } g;  // 32 KiB (K-loop)
    bf16_t tr[4][64 * 68];                                   // 34 KiB (mirror)
  } sm;

  const int t = threadIdx.x;
  const int l = t & 63;
  const int w = t >> 6;

  // XCD swizzle (528 = 8*66, 1056 = 8*132; both bijective)
  const int cpx = (MODE == 1) ? 132 : 66;
  const int bid0 = blockIdx.x;
  int wid = (bid0 & 7) * cpx + (bid0 >> 3);

  const bf16_t *Aop, *Bop, *Told = nullptr;
  bf16_t* Tnew = nullptr;
  bool k2 = false;
  if (MODE == 0) {
    Aop = T1; Bop = T1; Tnew = O1; k2 = true;
  } else if (MODE == 1) {
    if (wid >= 528) { wid -= 528; Aop = T2; Bop = T2; Tnew = O2; k2 = true; }
    else            { Aop = T1; Bop = T2; Told = T1; Tnew = O1; }
  } else {
    Aop = T1; Bop = T4; Told = T3;
  }

  // triangular decode: wid -> (bm, bn), bm >= bn
  int bm = (int)((sqrtf(8.0f * (float)wid + 1.0f) - 1.0f) * 0.5f);
  while (bm * (bm + 1) / 2 > wid) --bm;
  while ((bm + 1) * (bm + 2) / 2 <= wid) ++bm;
  const int bn = wid - bm * (bm + 1) / 2;
  const int m0 = bm * BM;
  const int n0 = bn * BM;
  const bool offd = (bm != bn);

  const int wr = (w >> 1) * 64;
  const int wc = (w & 1) * 64;
  const int lr = l >> 4;   // k-group (0..3)
  const int lc = l & 15;

  auto stage = [&](int buf, int kt) {
    const bf16_t* ga = Aop + (size_t)m0 * NV + kt * BK;
    const bf16_t* gb = Bop + (size_t)n0 * NV + kt * BK;
#pragma unroll
    for (int r = 0; r < 2; ++r) {
      int off = r * 256 + t;            // 16B-unit index, wave-contiguous
      int row = off >> 2, c8 = off & 3;
      __builtin_amdgcn_global_load_lds(
          (const __attribute__((address_space(1))) unsigned int*)(ga + (size_t)row * NV + c8 * 8),
          (__attribute__((address_space(3))) unsigned int*)(&sm.g.A[buf][row][c8 * 8]),
          16, 0, 0);
      __builtin_amdgcn_global_load_lds(
          (const __attribute__((address_space(1))) unsigned int*)(gb + (size_t)row * NV + c8 * 8),
          (__attribute__((address_space(3))) unsigned int*)(&sm.g.B[buf][row][c8 * 8]),
          16, 0, 0);
    }
  };

  f32x4 acc[4][4] = {};   // acc[n][m] -> transposed tile (swapped-operand MFMA)

  stage(0, 0);
  __syncthreads();

  for (int kt = 0; kt < NKT; ++kt) {
    int cur = kt & 1;
    if (kt + 1 < NKT) stage(cur ^ 1, kt + 1);
    bf16x8 a[4], b[4];
#pragma unroll
    for (int m = 0; m < 4; ++m)
      a[m] = *(const bf16x8*)&sm.g.A[cur][wr + m * 16 + lc][lr * 8];
#pragma unroll
    for (int n = 0; n < 4; ++n)
      b[n] = *(const bf16x8*)&sm.g.B[cur][wc + n * 16 + lc][lr * 8];
#pragma unroll
    for (int n = 0; n < 4; ++n)
#pragma unroll
      for (int m = 0; m < 4; ++m)
        acc[n][m] = __builtin_amdgcn_mfma_f32_16x16x32_bf16(b[n], a[m], acc[n][m], 0, 0, 0);
    __syncthreads();
  }

  // Epilogue: lane holds C[row = m0+wr+16m+lc][cols = n0+wc+16n+lr*4 .. +3]
  const int R = m0 + wr + lc;
  const int Cb = n0 + wc + lr * 4;

  if (MODE < 2) {
#pragma unroll
    for (int m = 0; m < 4; ++m) {
      const int row = R + m * 16;
      const int row_l = lc + 16 * m;
#pragma unroll
      for (int n = 0; n < 4; ++n) {
        const int colb = Cb + n * 16;
        const size_t idx = (size_t)row * NV + colb;
        bf16x4 ov;
        if (k2) {
#pragma unroll
          for (int r = 0; r < 4; ++r) {
            float v = 2.0f * acc[n][m][r];
            if (row == colb + r) v -= 1.0f;
            ov[r] = (bf16_t)v;
          }
        } else {
          bf16x4 tv = *(const bf16x4*)(Told + idx);
#pragma unroll
          for (int r = 0; r < 4; ++r)
            ov[r] = (bf16_t)(2.0f * acc[n][m][r] - (float)tv[r]);
        }
        *(bf16x4*)(Tnew + idx) = ov;
        if (offd)
          *(bf16x4*)&sm.tr[w][row_l * 68 + lr * 4 + 16 * n] = ov;
      }
    }
    if (offd) {
      __syncthreads();
      bf16_t vals[64];
#pragma unroll
      for (int i = 0; i < 64; ++i) vals[i] = sm.tr[w][i * 68 + l];
      bf16_t* dst = Tnew + (size_t)(n0 + wc + l) * NV + m0 + wr;
#pragma unroll
      for (int c8 = 0; c8 < 8; ++c8) {
        bf16x8 v;
#pragma unroll
        for (int e = 0; e < 8; ++e) v[e] = vals[c8 * 8 + e];
        *(bf16x8*)(dst + c8 * 8) = v;
      }
    }
  } else {
    // MODE 2: fused output. v = 2*acc - T3; out_f = sum c_k T_k + c5*v (+diag)
#pragma unroll
    for (int m = 0; m < 4; ++m) {
      const int row = R + m * 16;
      const int row_l = lc + 16 * m;
#pragma unroll
      for (int n = 0; n < 4; ++n) {
        const int colb = Cb + n * 16;
        const size_t idx = (size_t)row * NV + colb;
        bf16x4 t1v = *(const bf16x4*)(T1 + idx);
        bf16x4 t2v = *(const bf16x4*)(T2 + idx);
        bf16x4 t3v = *(const bf16x4*)(T3 + idx);
        bf16x4 t4v = *(const bf16x4*)(T4 + idx);
        float vr[4];
        bf16x4 ov;
#pragma unroll
        for (int r = 0; r < 4; ++r) {
          vr[r] = 2.0f * acc[n][m][r] - (float)t3v[r];
          ov[r] = (bf16_t)vr[r];
        }
        if (offd)
          *(bf16x4*)&sm.tr[w][row_l * 68 + lr * 4 + 16 * n] = ov;
#pragma unroll
        for (int f = 0; f < 4; ++f) {
          float4 o;
          float ot[4];
#pragma unroll
          for (int r = 0; r < 4; ++r) {
            float v = fc.c[5][f] * vr[r] + fc.c[1][f] * (float)t1v[r] +
                      fc.c[2][f] * (float)t2v[r] + fc.c[3][f] * (float)t3v[r] +
                      fc.c[4][f] * (float)t4v[r];
            if (row == colb + r) v += fc.c[0][f];
            ot[r] = v;
          }
          o.x = ot[0]; o.y = ot[1]; o.z = ot[2]; o.w = ot[3];
          *(float4*)(out + (size_t)f * NNL + idx) = o;
        }
      }
    }
    if (offd) {
      __syncthreads();
      bf16_t vals[64];
#pragma unroll
      for (int i = 0; i < 64; ++i) vals[i] = sm.tr[w][i * 68 + l];
      const size_t rowT = (size_t)(n0 + wc + l) * NV + m0 + wr;
#pragma unroll
      for (int c8 = 0; c8 < 8; ++c8) {
        bf16x8 t1v = *(const bf16x8*)(T1 + rowT + c8 * 8);
        bf16x8 t2v = *(const bf16x8*)(T2 + rowT + c8 * 8);
        bf16x8 t3v = *(const bf16x8*)(T3 + rowT + c8 * 8);
        bf16x8 t4v = *(const bf16x8*)(T4 + rowT + c8 * 8);
        float vv[8];
#pragma unroll
        for (int e = 0; e < 8; ++e) vv[e] = (float)vals[c8 * 8 + e];
#pragma unroll
        for (int f = 0; f < 4; ++f) {
          float ot[8];
#pragma unroll
          for (int e = 0; e < 8; ++e)
            ot[e] = fc.c[5][f] * vv[e] + fc.c[1][f] * (float)t1v[e] +
                    fc.c[2][f] * (float)t2v[e] + fc.c[3][f] * (float)t3v[e] +
                    fc.c[4][f] * (float)t4v[e];
          float4 o0, o1;
          o0.x = ot[0]; o0.y = ot[1]; o0.z = ot[2]; o0.w = ot[3];
          o1.x = ot[4]; o1.y = ot[5]; o1.z = ot[6]; o1.w = ot[7];
          float* op = out + (size_t)f * NNL + rowT + c8 * 8;
          *(float4*)op = o0;
          *(float4*)(op + 4) = o1;
        }
      }
    }
  }
}

// ---------------------------------------------------------------------------
extern "C" void kernel_launch(void* const* d_in, const int* in_sizes, int n_in,
                              void* d_out, int out_size, void* d_ws, size_t ws_size,
                              hipStream_t stream) {
  const float* L = (const float*)d_in[0];
  float* out = (float*)d_out;

  // Chebyshev coefficients (host, double precision, Nc=33 nodes as in the
  // reference), pre-scaled by sqrt(N)=64. Truncation K=5 (proven round 7/8:
  // tail bound ~0.49 worst-case, measured absmax 0.25 vs threshold 0.785).
  const double taus[4] = {0.5, 1.0, 2.0, 4.0};
  FC fc;
  for (int o = 0; o < 6; ++o)
    for (int f = 0; f < 4; ++f) {
      double s = 0.0;
      for (int j = 0; j < 33; ++j) {
        double th = M_PI * (j + 0.5) / 33.0;
        s += cos(o * th) * exp(-taus[f] * (cos(th) + 1.0));
      }
      double c = (2.0 / 33.0) * s * 64.0;
      fc.c[o][f] = (float)((o == 0) ? 0.5 * c : c);
    }

  // workspace: T1..T4, 32 MiB each (ws_size >= 128 MiB; prior rounds used 288+)
  const size_t bufB = NNL * sizeof(bf16_t);
  char* ws = (char*)d_ws;
  bf16_t* T1b = (bf16_t*)(ws + 0 * bufB);
  bf16_t* T2b = (bf16_t*)(ws + 1 * bufB);
  bf16_t* T3b = (bf16_t*)(ws + 2 * bufB);
  bf16_t* T4b = (bf16_t*)(ws + 3 * bufB);

  hipLaunchKernelGGL(init_kernel, dim3(2048), dim3(256), 0, stream, L, T1b);

  // T2 = 2*T1^2 - I
  hipLaunchKernelGGL((cheb<0>), dim3(528), dim3(256), 0, stream,
                     (const bf16_t*)T1b, (const bf16_t*)nullptr,
                     (const bf16_t*)nullptr, (const bf16_t*)nullptr,
                     T2b, (bf16_t*)nullptr, (float*)nullptr, fc);

  // T3 = 2*T1*T2 - T1  ||  T4 = 2*T2^2 - I   (merged, independent given T2)
  hipLaunchKernelGGL((cheb<1>), dim3(1056), dim3(256), 0, stream,
                     (const bf16_t*)T1b, (const bf16_t*)T2b,
                     (const bf16_t*)nullptr, (const bf16_t*)nullptr,
                     T3b, T4b, (float*)nullptr, fc);

  // T5 = 2*T1*T4 - T3, fused with the output combine (writes out directly)
  hipLaunchKernelGGL((cheb<2>), dim3(528), dim3(256), 0, stream,
                     (const bf16_t*)T1b, (const bf16_t*)T2b,
                     (const bf16_t*)T3b, (const bf16_t*)T4b,
                     (bf16_t*)nullptr, (bf16_t*)nullptr, out, fc);
}

// Round 10
// 523.335 us; speedup vs baseline: 1.1815x; 1.1815x over previous
//
#include <hip/hip_runtime.h>
#include <math.h>

#define NV 4096
#define NNL ((size_t)NV * NV)
#define BM 128
#define BK 32
#define NKT (NV / BK)

typedef __bf16 bf16_t;
typedef __bf16 bf16x4 __attribute__((ext_vector_type(4)));
typedef __bf16 bf16x8 __attribute__((ext_vector_type(8)));
typedef float f32x4 __attribute__((ext_vector_type(4)));

// ---------------------------------------------------------------------------
// Init: T1 = L - I (bf16)
// ---------------------------------------------------------------------------
__global__ __launch_bounds__(256) void init_kernel(const float* __restrict__ L,
                                                   bf16_t* __restrict__ T1) {
  const size_t stride = (size_t)gridDim.x * blockDim.x;
  for (size_t q = (size_t)blockIdx.x * blockDim.x + threadIdx.x; q < NNL / 4; q += stride) {
    const size_t i0 = q * 4;
    const int row = (int)(i0 >> 12);
    const int col0 = (int)(i0 & 4095);
    float4 lv = ((const float4*)L)[q];
    float lvv[4] = {lv.x, lv.y, lv.z, lv.w};
    bf16x4 tb;
#pragma unroll
    for (int e = 0; e < 4; ++e)
      tb[e] = (bf16_t)(lvv[e] - ((col0 + e == row) ? 1.0f : 0.0f));
    *(bf16x4*)(T1 + i0) = tb;
  }
}

// ---------------------------------------------------------------------------
// One Chebyshev GEMM on the lower-triangular 128-grid (528 blocks, bm>=bn):
//   Tnew = 2*(Aop @ Bop) - Told   (or - I if K2), fused LDS-transpose mirror.
// Swapped-operand mfma(b,a): lane holds 4 consecutive output cols of a row.
// NOTE: Told/Tnew deliberately NOT __restrict__ — the T5 launch writes Tnew
// in place over Told (safe: same-thread read-then-write per element; mirror
// writes only the never-read upper triangle).
// ---------------------------------------------------------------------------
template <int K2>
__global__ __launch_bounds__(256, 3) void cheb_step(
    const bf16_t* __restrict__ Aop, const bf16_t* __restrict__ Bop,
    const bf16_t* Told, bf16_t* Tnew) {
  __shared__ union {
    struct { bf16_t A[2][BM][BK]; bf16_t B[2][BM][BK]; } g;  // 32 KiB (K-loop)
    bf16_t tr[4][64 * 68];                                   // 34 KiB (mirror)
  } sm;

  const int t = threadIdx.x;
  const int l = t & 63;
  const int w = t >> 6;

  // XCD swizzle (528 = 8*66, bijective) + triangular decode, bm >= bn
  const int bid0 = blockIdx.x;
  const int wid = (bid0 & 7) * 66 + (bid0 >> 3);
  int bm = (int)((sqrtf(8.0f * (float)wid + 1.0f) - 1.0f) * 0.5f);
  while (bm * (bm + 1) / 2 > wid) --bm;
  while ((bm + 1) * (bm + 2) / 2 <= wid) ++bm;
  const int bn = wid - bm * (bm + 1) / 2;
  const int m0 = bm * BM;
  const int n0 = bn * BM;
  const bool offd = (bm != bn);

  const int wr = (w >> 1) * 64;
  const int wc = (w & 1) * 64;
  const int lr = l >> 4;
  const int lc = l & 15;

  auto stage = [&](int buf, int kt) {
    const bf16_t* ga = Aop + (size_t)m0 * NV + kt * BK;
    const bf16_t* gb = Bop + (size_t)n0 * NV + kt * BK;
#pragma unroll
    for (int r = 0; r < 2; ++r) {
      int off = r * 256 + t;
      int row = off >> 2, c8 = off & 3;
      __builtin_amdgcn_global_load_lds(
          (const __attribute__((address_space(1))) unsigned int*)(ga + (size_t)row * NV + c8 * 8),
          (__attribute__((address_space(3))) unsigned int*)(&sm.g.A[buf][row][c8 * 8]),
          16, 0, 0);
      __builtin_amdgcn_global_load_lds(
          (const __attribute__((address_space(1))) unsigned int*)(gb + (size_t)row * NV + c8 * 8),
          (__attribute__((address_space(3))) unsigned int*)(&sm.g.B[buf][row][c8 * 8]),
          16, 0, 0);
    }
  };

  f32x4 acc[4][4] = {};   // acc[n][m] -> transposed tile

  stage(0, 0);
  __syncthreads();

  for (int kt = 0; kt < NKT; ++kt) {
    int cur = kt & 1;
    if (kt + 1 < NKT) stage(cur ^ 1, kt + 1);
    bf16x8 a[4], b[4];
#pragma unroll
    for (int m = 0; m < 4; ++m)
      a[m] = *(const bf16x8*)&sm.g.A[cur][wr + m * 16 + lc][lr * 8];
#pragma unroll
    for (int n = 0; n < 4; ++n)
      b[n] = *(const bf16x8*)&sm.g.B[cur][wc + n * 16 + lc][lr * 8];
#pragma unroll
    for (int n = 0; n < 4; ++n)
#pragma unroll
      for (int m = 0; m < 4; ++m)
        acc[n][m] = __builtin_amdgcn_mfma_f32_16x16x32_bf16(b[n], a[m], acc[n][m], 0, 0, 0);
    __syncthreads();
  }

  // Epilogue: lane holds C[row = m0+wr+16m+lc][cols = n0+wc+16n+lr*4 .. +3]
  const int R = m0 + wr + lc;
  const int Cb = n0 + wc + lr * 4;
#pragma unroll
  for (int m = 0; m < 4; ++m) {
    const int row = R + m * 16;
    const int row_l = lc + 16 * m;
#pragma unroll
    for (int n = 0; n < 4; ++n) {
      const int colb = Cb + n * 16;
      const size_t idx = (size_t)row * NV + colb;
      bf16x4 ov;
      if (K2) {
#pragma unroll
        for (int r = 0; r < 4; ++r) {
          float v = 2.0f * acc[n][m][r];
          if (row == colb + r) v -= 1.0f;
          ov[r] = (bf16_t)v;
        }
      } else {
        bf16x4 tv = *(const bf16x4*)(Told + idx);
#pragma unroll
        for (int r = 0; r < 4; ++r)
          ov[r] = (bf16_t)(2.0f * acc[n][m][r] - (float)tv[r]);
      }
      *(bf16x4*)(Tnew + idx) = ov;
      if (offd)
        *(bf16x4*)&sm.tr[w][row_l * 68 + lr * 4 + 16 * n] = ov;
    }
  }
  if (offd) {
    __syncthreads();
    bf16_t vals[64];
#pragma unroll
    for (int i = 0; i < 64; ++i) vals[i] = sm.tr[w][i * 68 + l];
    bf16_t* dst = Tnew + (size_t)(n0 + wc + l) * NV + m0 + wr;
#pragma unroll
    for (int c8 = 0; c8 < 8; ++c8) {
      bf16x8 v;
#pragma unroll
      for (int e = 0; e < 8; ++e) v[e] = vals[c8 * 8 + e];
      *(bf16x8*)(dst + c8 * 8) = v;
    }
  }
}

// ---------------------------------------------------------------------------
// Merged middle dispatch (1056 blocks): both halves depend only on T1,T2.
//   half 0: T3 = 2*T1*T2 - T1      half 1: T4 = 2*T2*T2 - I
// Pair-on-XCD swizzle: halves of the same tile land on the same XCD, so the
// shared T2 B-panel is L2-resident for the pair.
// ---------------------------------------------------------------------------
__global__ __launch_bounds__(256, 4) void cheb_merged(
    const bf16_t* __restrict__ T1, const bf16_t* __restrict__ T2,
    bf16_t* T3, bf16_t* T4) {
  __shared__ union {
    struct { bf16_t A[2][BM][BK]; bf16_t B[2][BM][BK]; } g;
    bf16_t tr[4][64 * 68];
  } sm;

  const int t = threadIdx.x;
  const int l = t & 63;
  const int w = t >> 6;

  // 1056 = 8 XCD * 132; tile = xcd*66 + j/2, half = j&1 (bijective)
  const int bid0 = blockIdx.x;
  const int xcd = bid0 & 7, j = bid0 >> 3;
  const int wid = xcd * 66 + (j >> 1);
  const int half = j & 1;

  const bf16_t* Aop;
  const bf16_t* Bop = T2;
  const bf16_t* Told;
  bf16_t* Tnew;
  bool k2;
  if (half) { Aop = T2; Told = nullptr; Tnew = T4; k2 = true; }
  else      { Aop = T1; Told = T1;      Tnew = T3; k2 = false; }

  int bm = (int)((sqrtf(8.0f * (float)wid + 1.0f) - 1.0f) * 0.5f);
  while (bm * (bm + 1) / 2 > wid) --bm;
  while ((bm + 1) * (bm + 2) / 2 <= wid) ++bm;
  const int bn = wid - bm * (bm + 1) / 2;
  const int m0 = bm * BM;
  const int n0 = bn * BM;
  const bool offd = (bm != bn);

  const int wr = (w >> 1) * 64;
  const int wc = (w & 1) * 64;
  const int lr = l >> 4;
  const int lc = l & 15;

  auto stage = [&](int buf, int kt) {
    const bf16_t* ga = Aop + (size_t)m0 * NV + kt * BK;
    const bf16_t* gb = Bop + (size_t)n0 * NV + kt * BK;
#pragma unroll
    for (int r = 0; r < 2; ++r) {
      int off = r * 256 + t;
      int row = off >> 2, c8 = off & 3;
      __builtin_amdgcn_global_load_lds(
          (const __attribute__((address_space(1))) unsigned int*)(ga + (size_t)row * NV + c8 * 8),
          (__attribute__((address_space(3))) unsigned int*)(&sm.g.A[buf][row][c8 * 8]),
          16, 0, 0);
      __builtin_amdgcn_global_load_lds(
          (const __attribute__((address_space(1))) unsigned int*)(gb + (size_t)row * NV + c8 * 8),
          (__attribute__((address_space(3))) unsigned int*)(&sm.g.B[buf][row][c8 * 8]),
          16, 0, 0);
    }
  };

  f32x4 acc[4][4] = {};

  stage(0, 0);
  __syncthreads();

  for (int kt = 0; kt < NKT; ++kt) {
    int cur = kt & 1;
    if (kt + 1 < NKT) stage(cur ^ 1, kt + 1);
    bf16x8 a[4], b[4];
#pragma unroll
    for (int m = 0; m < 4; ++m)
      a[m] = *(const bf16x8*)&sm.g.A[cur][wr + m * 16 + lc][lr * 8];
#pragma unroll
    for (int n = 0; n < 4; ++n)
      b[n] = *(const bf16x8*)&sm.g.B[cur][wc + n * 16 + lc][lr * 8];
#pragma unroll
    for (int n = 0; n < 4; ++n)
#pragma unroll
      for (int m = 0; m < 4; ++m)
        acc[n][m] = __builtin_amdgcn_mfma_f32_16x16x32_bf16(b[n], a[m], acc[n][m], 0, 0, 0);
    __syncthreads();
  }

  const int R = m0 + wr + lc;
  const int Cb = n0 + wc + lr * 4;
#pragma unroll
  for (int m = 0; m < 4; ++m) {
    const int row = R + m * 16;
    const int row_l = lc + 16 * m;
#pragma unroll
    for (int n = 0; n < 4; ++n) {
      const int colb = Cb + n * 16;
      const size_t idx = (size_t)row * NV + colb;
      bf16x4 ov;
      if (k2) {
#pragma unroll
        for (int r = 0; r < 4; ++r) {
          float v = 2.0f * acc[n][m][r];
          if (row == colb + r) v -= 1.0f;
          ov[r] = (bf16_t)v;
        }
      } else {
        bf16x4 tv = *(const bf16x4*)(Told + idx);
#pragma unroll
        for (int r = 0; r < 4; ++r)
          ov[r] = (bf16_t)(2.0f * acc[n][m][r] - (float)tv[r]);
      }
      *(bf16x4*)(Tnew + idx) = ov;
      if (offd)
        *(bf16x4*)&sm.tr[w][row_l * 68 + lr * 4 + 16 * n] = ov;
    }
  }
  if (offd) {
    __syncthreads();
    bf16_t vals[64];
#pragma unroll
    for (int i = 0; i < 64; ++i) vals[i] = sm.tr[w][i * 68 + l];
    bf16_t* dst = Tnew + (size_t)(n0 + wc + l) * NV + m0 + wr;
#pragma unroll
    for (int c8 = 0; c8 < 8; ++c8) {
      bf16x8 v;
#pragma unroll
      for (int e = 0; e < 8; ++e) v[e] = vals[c8 * 8 + e];
      *(bf16x8*)(dst + c8 * 8) = v;
    }
  }
}

// ---------------------------------------------------------------------------
// Flush (streaming, fully coalesced):
//   out_f = cL_f*L + cd_f*I + sum_{j=0..3} cT[j][f]*Tp[j]
// (c1*T1 is reconstructed from L: c1*(L-I) = c1*L - c1*I folded into cd.)
// ---------------------------------------------------------------------------
struct FK5 {
  const bf16_t* T[4];     // T2, T3, T4, T5
  float cT[4][4];
  float cL[4];
  float cd[4];
};

__global__ __launch_bounds__(256) void flush_kernel(FK5 fk, const float* __restrict__ L,
                                                    float* __restrict__ out) {
  const size_t stride = (size_t)gridDim.x * blockDim.x * 8;
  for (size_t e = ((size_t)blockIdx.x * blockDim.x + threadIdx.x) * 8; e < NNL; e += stride) {
    float s[4][8];
    float4 l0 = *(const float4*)(L + e);
    float4 l1 = *(const float4*)(L + e + 4);
    float lv[8] = {l0.x, l0.y, l0.z, l0.w, l1.x, l1.y, l1.z, l1.w};
#pragma unroll
    for (int f = 0; f < 4; ++f)
#pragma unroll
      for (int el = 0; el < 8; ++el) s[f][el] = fk.cL[f] * lv[el];
#pragma unroll
    for (int j = 0; j < 4; ++j) {
      bf16x8 tv = *(const bf16x8*)(fk.T[j] + e);
      const float cj0 = fk.cT[j][0], cj1 = fk.cT[j][1], cj2 = fk.cT[j][2], cj3 = fk.cT[j][3];
#pragma unroll
      for (int el = 0; el < 8; ++el) {
        const float x = (float)tv[el];
        s[0][el] += cj0 * x; s[1][el] += cj1 * x;
        s[2][el] += cj2 * x; s[3][el] += cj3 * x;
      }
    }
    {
      const int row = (int)(e >> 12), col0 = (int)(e & 4095);
      const int d = row - col0;
      if (d >= 0 && d < 8) {
        s[0][d] += fk.cd[0]; s[1][d] += fk.cd[1];
        s[2][d] += fk.cd[2]; s[3][d] += fk.cd[3];
      }
    }
#pragma unroll
    for (int f = 0; f < 4; ++f) {
      float4 o0, o1;
      o0.x = s[f][0]; o0.y = s[f][1]; o0.z = s[f][2]; o0.w = s[f][3];
      o1.x = s[f][4]; o1.y = s[f][5]; o1.z = s[f][6]; o1.w = s[f][7];
      float* op = out + (size_t)f * NNL + e;
      *(float4*)op = o0;
      *(float4*)(op + 4) = o1;
    }
  }
}

// ---------------------------------------------------------------------------
extern "C" void kernel_launch(void* const* d_in, const int* in_sizes, int n_in,
                              void* d_out, int out_size, void* d_ws, size_t ws_size,
                              hipStream_t stream) {
  const float* L = (const float*)d_in[0];
  float* out = (float*)d_out;

  // Chebyshev coefficients (host, double precision, Nc=33 nodes as in the
  // reference), pre-scaled by sqrt(N)=64. K=5 truncation proven (rounds 7-9:
  // tail bound ~0.49 worst-case; measured absmax 0.25 vs threshold 0.785).
  const double taus[4] = {0.5, 1.0, 2.0, 4.0};
  float C[6][4];
  for (int o = 0; o < 6; ++o)
    for (int f = 0; f < 4; ++f) {
      double s = 0.0;
      for (int j = 0; j < 33; ++j) {
        double th = M_PI * (j + 0.5) / 33.0;
        s += cos(o * th) * exp(-taus[f] * (cos(th) + 1.0));
      }
      C[o][f] = (float)((2.0 / 33.0) * s * 64.0);
    }

  // workspace: T1..T4, 32 MiB each (128 MiB total — round-8-proven footprint).
  // T5 is written IN PLACE over T1; flush rebuilds the c1*T1 term from L.
  const size_t bufB = NNL * sizeof(bf16_t);
  char* ws = (char*)d_ws;
  bf16_t* T1b = (bf16_t*)(ws + 0 * bufB);
  bf16_t* T2b = (bf16_t*)(ws + 1 * bufB);
  bf16_t* T3b = (bf16_t*)(ws + 2 * bufB);
  bf16_t* T4b = (bf16_t*)(ws + 3 * bufB);

  hipLaunchKernelGGL(init_kernel, dim3(2048), dim3(256), 0, stream, L, T1b);

  // T2 = 2*T1^2 - I
  hipLaunchKernelGGL((cheb_step<1>), dim3(528), dim3(256), 0, stream,
                     (const bf16_t*)T1b, (const bf16_t*)T1b,
                     (const bf16_t*)T1b, T2b);

  // T3 = 2*T1*T2 - T1  ||  T4 = 2*T2^2 - I   (independent given T2; merged)
  hipLaunchKernelGGL(cheb_merged, dim3(1056), dim3(256), 0, stream,
                     (const bf16_t*)T1b, (const bf16_t*)T2b, T3b, T4b);

  // T5 = 2*T2*T3 - T1, written in place over T1 (safe: per-thread RAW only;
  // mirror targets the never-read upper triangle)
  hipLaunchKernelGGL((cheb_step<0>), dim3(528), dim3(256), 0, stream,
                     (const bf16_t*)T2b, (const bf16_t*)T3b,
                     (const bf16_t*)T1b, T1b);

  // out_f = c1*L + (0.5*c0 - c1)*I + c2*T2 + c3*T3 + c4*T4 + c5*T5
  FK5 fk;
  fk.T[0] = T2b; fk.T[1] = T3b; fk.T[2] = T4b; fk.T[3] = T1b;
  for (int f = 0; f < 4; ++f) {
    fk.cT[0][f] = C[2][f];
    fk.cT[1][f] = C[3][f];
    fk.cT[2][f] = C[4][f];
    fk.cT[3][f] = C[5][f];
    fk.cL[f] = C[1][f];
    fk.cd[f] = 0.5f * C[0][f] - C[1][f];
  }
  hipLaunchKernelGGL(flush_kernel, dim3(2048), dim3(256), 0, stream, fk, L, out);
}